// Round 9
// baseline (526.178 us; speedup 1.0000x reference)
//
#include <hip/hip_runtime.h>
#include <hip/hip_bf16.h>
#include <math.h>

#define NTOK 4096   // B*S
#define DDIM 1024
#define HDIM 4096
#define EEXP 8
#define NPAIR_PAD (2*NTOK + EEXP*128)   // 9216 max (128-padded segments); alloc 10240
#define NPALLOC 10240

#define BM 128
#define BN 256
#define BK 64
#define G1GRID 1280   // >= 8*ceil(max wl1/8)
#define G2GRID 640

typedef __attribute__((ext_vector_type(8))) short short8;
typedef __attribute__((ext_vector_type(4))) short short4v;
typedef __attribute__((ext_vector_type(4))) float f32x4;

static __device__ __forceinline__ unsigned short f2bf(float f){
  unsigned int u = __float_as_uint(f);
  u += 0x7FFFu + ((u >> 16) & 1u);
  return (unsigned short)(u >> 16);
}
static __device__ __forceinline__ float bf2f(short s){
  return __uint_as_float(((unsigned int)(unsigned short)s) << 16);
}
static __device__ __forceinline__ void gload16(const void* g, void* l){
  __builtin_amdgcn_global_load_lds(
      (const __attribute__((address_space(1))) void*)g,
      (__attribute__((address_space(3))) void*)l, 16, 0, 0);
}
static __device__ __forceinline__ void BAR(){
  asm volatile("" ::: "memory");
  __builtin_amdgcn_s_barrier();
  asm volatile("" ::: "memory");
}

// convert one 16B-chunk of w (f32) -> wb (bf16, pre-swizzled within 8-chunk groups)
static __device__ __forceinline__ void conv_chunk(const float* __restrict__ w,
    short* __restrict__ wb, int klog2, size_t i){
  const int cshift = klog2 - 3;
  size_t n = i >> cshift;
  int c = (int)(i & ((1u << cshift) - 1u));
  int csw = (c & ~7) | ((c ^ (int)n) & 7);
  const float* src = w + (n << klog2) + (size_t)csw * 8;
  f32x4 a = ((const f32x4*)src)[0];
  f32x4 b = ((const f32x4*)src)[1];
  short8 o;
#pragma unroll
  for (int j = 0; j < 4; ++j){ o[j] = (short)f2bf(a[j]); o[j+4] = (short)f2bf(b[j]); }
  *(short8*)(wb + (n << klog2) + (size_t)c * 8) = o;
}

// ---- fused: blocks [0,16384) convert w1; blocks [16384,17408) gate ----
__global__ __launch_bounds__(256) void conv1_gate_kernel(
    const float* __restrict__ w1, short* __restrict__ wb,
    const float* __restrict__ x, const float* __restrict__ gw,
    const float* __restrict__ gb, float* __restrict__ outF,
    short* __restrict__ xb, int2* __restrict__ te, float2* __restrict__ tw,
    int* __restrict__ cnt){
  if (blockIdx.x < 16384){
    conv_chunk(w1, wb, 10, (size_t)blockIdx.x * 256 + threadIdx.x);
    return;
  }
  const int t = (blockIdx.x - 16384) * 4 + (threadIdx.x >> 6);
  const int l = threadIdx.x & 63;
  const f32x4* xr = (const f32x4*)(x + (size_t)t * DDIM);
  f32x4 xv[4];
#pragma unroll
  for (int j = 0; j < 4; ++j) xv[j] = xr[l + 64*j];
#pragma unroll
  for (int j = 0; j < 4; ++j){
    short4v o;
#pragma unroll
    for (int q = 0; q < 4; ++q) o[q] = (short)f2bf(xv[j][q]);
    ((short4v*)(xb + (size_t)t * DDIM))[l + 64*j] = o;
  }
  float acc[EEXP];
#pragma unroll
  for (int e = 0; e < EEXP; ++e) acc[e] = 0.f;
#pragma unroll
  for (int j = 0; j < 4; ++j){
#pragma unroll
    for (int e = 0; e < EEXP; ++e){
      f32x4 gv = ((const f32x4*)(gw + (size_t)e*DDIM))[l + 64*j];
      acc[e] += xv[j][0]*gv[0] + xv[j][1]*gv[1] + xv[j][2]*gv[2] + xv[j][3]*gv[3];
    }
  }
#pragma unroll
  for (int e = 0; e < EEXP; ++e){
#pragma unroll
    for (int off = 32; off > 0; off >>= 1) acc[e] += __shfl_xor(acc[e], off);
  }
  if (l == 0){
    float lg[EEXP];
#pragma unroll
    for (int e = 0; e < EEXP; ++e) lg[e] = acc[e] + gb[e];
    int e0 = 0; float v0 = lg[0];
#pragma unroll
    for (int e = 1; e < EEXP; ++e) if (lg[e] > v0){ v0 = lg[e]; e0 = e; }
    int e1 = -1; float v1 = -1e30f;
#pragma unroll
    for (int e = 0; e < EEXP; ++e) if (e != e0 && lg[e] > v1){ v1 = lg[e]; e1 = e; }
    float r  = expf(v1 - v0);
    float w0 = 1.f / (1.f + r);
    float w1s = r / (1.f + r);
    outF[(size_t)NTOK*DDIM + 2*t    ] = (float)e0;
    outF[(size_t)NTOK*DDIM + 2*t + 1] = (float)e1;
    te[t] = make_int2(e0, e1);
    tw[t] = make_float2(w0, w1s);
    atomicAdd(&cnt[e0], 1);
    atomicAdd(&cnt[e1], 1);
  }
}

// meta: [0:8)cnt [8:16)offs [16:24)cur [32:40)base1 [40:48)len1 [48:56)base2 [56:64)len2
//       [64:64+1280) wl1 | [1344:1344+640) wl2.  item: e | mt<<3 | n<<8 | ks<<12
__global__ void scan_kernel(int* __restrict__ meta){
  if (threadIdx.x != 0) return;
  int s = 0, tiles[EEXP];
  for (int e = 0; e < EEXP; ++e){
    meta[8+e] = s;
    int c = meta[e];
    tiles[e] = (c + 127) >> 7;
    s += (c + 127) & ~127;
  }
  int* wl1 = meta + 64;
  int n1 = 0;
  for (int e = 0; e < EEXP; ++e)
    for (int n = 0; n < 16; ++n)            // n outer, m inner: B-slice stays hot
      for (int mt = 0; mt < tiles[e]; ++mt)
        wl1[n1++] = e | (mt << 3) | (n << 8);
  int q = n1 >> 3, r = n1 & 7;
  for (int x = 0; x < 8; ++x){
    meta[32+x] = x*q + (x < r ? x : r);
    meta[40+x] = q + (x < r ? 1 : 0);
  }
  int* wl2 = meta + 1344;
  int n2 = 0;
  for (int e = 0; e < EEXP; ++e)
    for (int k = 0; k < 2; ++k)
      for (int n = 0; n < 4; ++n)
        for (int mt = 0; mt < tiles[e]; ++mt)
          wl2[n2++] = e | (mt << 3) | (n << 8) | (k << 12);
  q = n2 >> 3; r = n2 & 7;
  for (int x = 0; x < 8; ++x){
    meta[48+x] = x*q + (x < r ? x : r);
    meta[56+x] = q + (x < r ? 1 : 0);
  }
}

__global__ __launch_bounds__(256) void scatter_kernel(const int2* __restrict__ te,
    const int* __restrict__ offs, int* __restrict__ cur,
    int* __restrict__ tokp, int* __restrict__ pidx){
  int t = blockIdx.x * blockDim.x + threadIdx.x;
  if (t >= NTOK) return;
  int2 e = te[t];
  int p0 = offs[e.x] + atomicAdd(&cur[e.x], 1);
  tokp[p0] = t; pidx[2*t] = p0;
  int p1 = offs[e.y] + atomicAdd(&cur[e.y], 1);
  tokp[p1] = t; pidx[2*t+1] = p1;
}

// ---- grouped GEMM: 128x256xBK64, 8 waves, 64KB LDS (A dbuf + B single), 2 blocks/CU ----
// PHASE 1 (+fused convert of w2 in extra blocks): h = GELU(gather(xb) @ w1b^T + b1)
// PHASE 2: y[ks] = h @ w2b^T (K-split 2, unweighted bf16 partials)
template<int PHASE, int KDIM, int NDIM, int KSPLIT>
__global__ __launch_bounds__(512, 4) void moe_gemm(
    const short* __restrict__ Ab, const short* __restrict__ Wb,
    const float* __restrict__ bias, const int* __restrict__ meta,
    const int* __restrict__ tokp,
    short* __restrict__ O0, short* __restrict__ O1,
    const float* __restrict__ wsrc, short* __restrict__ wdst, int nconv){
  constexpr int GRID = (PHASE == 1) ? G1GRID : G2GRID;
  if (PHASE == 1 && (int)blockIdx.x >= GRID){
    size_t i = (size_t)(blockIdx.x - GRID) * 512 + threadIdx.x;   // fused convert w2
    if (nconv) conv_chunk(wsrc, wdst, 12, i);
    return;
  }
  constexpr int KLEN = KDIM / KSPLIT;
  constexpr int NK = KLEN / BK;
  const int xcd  = blockIdx.x & 7;
  const int slot = blockIdx.x >> 3;
  if (slot >= meta[(PHASE == 1 ? 40 : 56) + xcd]) return;
  const int item = meta[(PHASE == 1 ? 64 : 1344)
                        + meta[(PHASE == 1 ? 32 : 48) + xcd] + slot];
  const int e  = item & 7;
  const int m0 = ((item >> 3) & 31) << 7;
  const int n0 = ((item >> 8) & 15) << 8;
  const int ks = (item >> 12) & 1;
  const int cnt = meta[e];
  const int off = meta[8 + e];
  const int mrows = min(BM, cnt - m0);
  const int kbase = ks * KLEN;
  short* O = ks ? O1 : O0;

  __shared__ __align__(16) short SMEM[32768];   // 64KB: A[0] 16K | A[1] 16K | B 32K

  const int tid  = threadIdx.x;
  const int lane = tid & 63;
  const int wid  = tid >> 6;
  const int wr   = wid >> 2;   // 0..1 -> 64 rows each
  const int wc   = wid & 3;    // 0..3 -> 64 cols each

  const short* wE = Wb + (size_t)e * NDIM * KDIM;
  unsigned aOff[2], bOff[4];
  int ldsOff[4];
#pragma unroll
  for (int s = 0; s < 4; ++s){
    const int rb = wid * 8 + s * 64;            // wave-uniform base row
    ldsOff[s] = rb * BK;                        // shorts; HW adds lane*16B
    const int r = rb + (lane >> 3);
    bOff[s] = (unsigned)((n0 + r) * KDIM + kbase + ((lane & 7) << 3));
    if (s < 2){
      if (PHASE == 1){
        const int tok = tokp[off + m0 + r];
        aOff[s] = (unsigned)(tok * KDIM + (((lane & 7) ^ (r & 7)) << 3));
      } else {
        aOff[s] = (unsigned)((off + m0 + r) * KDIM + kbase + ((lane & 7) << 3));
      }
    }
  }

  f32x4 acc[4][4];
#pragma unroll
  for (int ii = 0; ii < 4; ++ii)
#pragma unroll
    for (int j = 0; j < 4; ++j) acc[ii][j] = (f32x4){0.f, 0.f, 0.f, 0.f};

  // prologue: stage tile 0 (A->buf0, B)
  gload16(Ab + (size_t)aOff[0], SMEM + ldsOff[0]);
  gload16(Ab + (size_t)aOff[1], SMEM + ldsOff[1]);
#pragma unroll
  for (int s = 0; s < 4; ++s) gload16(wE + (size_t)bOff[s], SMEM + 16384 + ldsOff[s]);
  asm volatile("s_waitcnt vmcnt(0)" ::: "memory");
  BAR();

  for (int t = 0; t < NK; ++t){
    const short* Ac = SMEM + (t & 1) * 8192;
    // phase-0 reads: ALL of B into regs + A row-frag 0
    short8 bfr[4][2], af[2];
#pragma unroll
    for (int j = 0; j < 4; ++j){
      const int rB = wc * 64 + j * 16 + (lane & 15);
#pragma unroll
      for (int kk = 0; kk < 2; ++kk){
        const int bc = kk * 64 + (lane >> 4) * 16;
        bfr[j][kk] = *(const short8*)&SMEM[16384 + rB * BK + ((bc ^ ((rB & 7) << 4)) >> 1)];
      }
    }
    {
      const int rA = wr * 64 + (lane & 15);
#pragma unroll
      for (int kk = 0; kk < 2; ++kk){
        const int bc = kk * 64 + (lane >> 4) * 16;
        af[kk] = *(const short8*)&Ac[rA * BK + ((bc ^ ((rA & 7) << 4)) >> 1)];
      }
    }
    asm volatile("s_waitcnt lgkmcnt(0)" ::: "memory");
    __builtin_amdgcn_sched_barrier(0);
    BAR();                                   // bar1: every wave's B reads retired
    if (t + 1 < NK){                         // stage t+1: B reusable, A -> other buf
      const int k1 = (t + 1) * BK;
      short* An = SMEM + ((t + 1) & 1) * 8192;
      gload16(Ab + (size_t)aOff[0] + k1, An + ldsOff[0]);
      gload16(Ab + (size_t)aOff[1] + k1, An + ldsOff[1]);
#pragma unroll
      for (int s = 0; s < 4; ++s)
        gload16(wE + (size_t)bOff[s] + k1, SMEM + 16384 + ldsOff[s]);
    }
    __builtin_amdgcn_s_setprio(1);
#pragma unroll
    for (int j = 0; j < 4; ++j)
#pragma unroll
      for (int kk = 0; kk < 2; ++kk)
        acc[0][j] = __builtin_amdgcn_mfma_f32_16x16x32_bf16(af[kk], bfr[j][kk], acc[0][j], 0, 0, 0);
    __builtin_amdgcn_s_setprio(0);
#pragma unroll
    for (int q = 1; q < 4; ++q){
      short8 a2[2];
      const int rA = wr * 64 + q * 16 + (lane & 15);
#pragma unroll
      for (int kk = 0; kk < 2; ++kk){
        const int bc = kk * 64 + (lane >> 4) * 16;
        a2[kk] = *(const short8*)&Ac[rA * BK + ((bc ^ ((rA & 7) << 4)) >> 1)];
      }
      __builtin_amdgcn_s_setprio(1);
#pragma unroll
      for (int j = 0; j < 4; ++j)
#pragma unroll
        for (int kk = 0; kk < 2; ++kk)
          acc[q][j] = __builtin_amdgcn_mfma_f32_16x16x32_bf16(a2[kk], bfr[j][kk], acc[q][j], 0, 0, 0);
      __builtin_amdgcn_s_setprio(0);
    }
    if (t + 1 < NK) asm volatile("s_waitcnt vmcnt(0)" ::: "memory");  // ~600cyc flight
    BAR();                                   // bar2: next tile fully in LDS
  }

  // ---- epilogue: acc -> LDS T[128][256] bf16 (swizzled) -> coalesced stores ----
  short* T = SMEM;
#pragma unroll
  for (int j = 0; j < 4; ++j){
    const int n = n0 + wc * 64 + j * 16 + (lane & 15);
    const float bv = (PHASE == 1) ? bias[(size_t)e * NDIM + n] : 0.f;
#pragma unroll
    for (int ii = 0; ii < 4; ++ii){
#pragma unroll
      for (int q = 0; q < 4; ++q){
        const int r = wr * 64 + ii * 16 + (lane >> 4) * 4 + q;
        const int c = wc * 64 + j * 16 + (lane & 15);
        float v = acc[ii][j][q];
        if (PHASE == 1){
          v += bv;
          float u2 = v * (1.5957691216057308f + 0.07135481627014317f * v * v);
          v = v / (1.f + __expf(-u2));       // tanh-GELU (err ~1e-3 << 0.14)
        }
        T[r * 256 + (c ^ ((r & 7) << 3))] = (short)f2bf(v);
      }
    }
  }
  __syncthreads();
  {
    const int r = tid >> 2;                  // 128 rows, 4 threads/row
    const int key = r & 7;
    const size_t rowb = (size_t)(off + m0 + r) * NDIM + n0;
#pragma unroll
    for (int c8 = 0; c8 < 8; ++c8){
      const int ci = (tid & 3) * 8 + c8;
      const int pc = (ci & ~7) | ((ci ^ key) & 7);
      short8 v = *(const short8*)&T[r * 256 + pc * 8];
      const int gcc = (PHASE == 1) ? pc : ci;   // P1: keep pre-swizzled; P2: linear
      if (r < mrows) *(short8*)&O[rowb + (size_t)gcc * 8] = v;
    }
  }
}

__global__ __launch_bounds__(512) void conv2_kernel(const float* __restrict__ w2,
    short* __restrict__ wb){
  conv_chunk(w2, wb, 12, (size_t)blockIdx.x * 512 + threadIdx.x);
}

// ---- combine: out[t] = w0*(y0[p0]+y1[p0]+b2[e0]) + w1*(y0[p1]+y1[p1]+b2[e1]) ----
__global__ __launch_bounds__(256) void combine_kernel(
    const short* __restrict__ y0, const short* __restrict__ y1,
    const int2* __restrict__ te, const float2* __restrict__ tw,
    const int* __restrict__ pidx, const float* __restrict__ b2,
    float* __restrict__ outF){
  const int t = blockIdx.x;
  const int d = threadIdx.x * 4;
  int2 e = te[t]; float2 w = tw[t];
  int p0 = pidx[2*t], p1 = pidx[2*t+1];
  short4v a0 = *(const short4v*)&y0[(size_t)p0 * DDIM + d];
  short4v a1 = *(const short4v*)&y1[(size_t)p0 * DDIM + d];
  short4v c0 = *(const short4v*)&y0[(size_t)p1 * DDIM + d];
  short4v c1 = *(const short4v*)&y1[(size_t)p1 * DDIM + d];
  f32x4 b0 = *(const f32x4*)&b2[(size_t)e.x * DDIM + d];
  f32x4 b1 = *(const f32x4*)&b2[(size_t)e.y * DDIM + d];
  f32x4 o;
#pragma unroll
  for (int q = 0; q < 4; ++q){
    float s0 = bf2f(a0[q]) + bf2f(a1[q]) + b0[q];
    float s1 = bf2f(c0[q]) + bf2f(c1[q]) + b1[q];
    o[q] = w.x * s0 + w.y * s1;
  }
  *(f32x4*)&outF[(size_t)t * DDIM + d] = o;
}

extern "C" void kernel_launch(void* const* d_in, const int* in_sizes, int n_in,
                              void* d_out, int out_size, void* d_ws, size_t ws_size,
                              hipStream_t stream){
  const float* x  = (const float*)d_in[0];
  const float* gw = (const float*)d_in[1];
  const float* gb = (const float*)d_in[2];
  const float* w1 = (const float*)d_in[3];
  const float* b1 = (const float*)d_in[4];
  const float* w2 = (const float*)d_in[5];
  const float* b2 = (const float*)d_in[6];
  float* outF = (float*)d_out;

  char* p = (char*)d_ws;
  short* xb = (short*)p;  p += (size_t)NTOK * DDIM * 2;          // 8.4 MB
  short* h  = (short*)p;  p += (size_t)NPALLOC * HDIM * 2;       // 83.9 MB
  short* wb = (short*)p;  p += (size_t)EEXP * HDIM * DDIM * 2;   // 67.1 MB (w1b)
  short* y0 = (short*)p;  p += (size_t)NPALLOC * DDIM * 2;       // 21 MB
  short* y1 = (short*)p;  p += (size_t)NPALLOC * DDIM * 2;       // 21 MB
  int*   tokp = (int*)p;  p += (size_t)NPALLOC * 4;
  int*   pidx = (int*)p;  p += (size_t)2 * NTOK * 4;
  int2*  te   = (int2*)p; p += (size_t)NTOK * 8;
  float2* tw  = (float2*)p; p += (size_t)NTOK * 8;
  int* meta = (int*)p;    p += 8192 * 4;
  short* wb2 = (short*)p; p += (size_t)EEXP * HDIM * DDIM * 2;   // 67.1 MB (w2b, optional)
  const bool dualW = ws_size >= (size_t)(p - (char*)d_ws);

  hipMemsetAsync(meta, 0, 24 * sizeof(int), stream);
  hipMemsetAsync(tokp, 0, (size_t)NPALLOC * 4, stream);
  conv1_gate_kernel<<<16384 + NTOK / 4, 256, 0, stream>>>(
      w1, wb, x, gw, gb, outF, xb, te, tw, meta);
  scan_kernel<<<1, 64, 0, stream>>>(meta);
  scatter_kernel<<<(NTOK + 255) / 256, 256, 0, stream>>>(te, meta + 8, meta + 16, tokp, pidx);
  if (dualW){
    // GEMM1 blocks + 8192 fused convert-w2 blocks (independent buffers)
    moe_gemm<1, DDIM, HDIM, 1><<<G1GRID + 8192, 512, 0, stream>>>(
        xb, wb, b1, meta, tokp, h, h, w2, wb2, 1);
    moe_gemm<2, HDIM, DDIM, 2><<<G2GRID, 512, 0, stream>>>(
        h, wb2, nullptr, meta, tokp, y0, y1, nullptr, nullptr, 0);
  } else {
    moe_gemm<1, DDIM, HDIM, 1><<<G1GRID, 512, 0, stream>>>(
        xb, wb, b1, meta, tokp, h, h, nullptr, nullptr, 0);
    conv2_kernel<<<8192, 512, 0, stream>>>(w2, wb);
    moe_gemm<2, HDIM, DDIM, 2><<<G2GRID, 512, 0, stream>>>(
        h, wb, nullptr, meta, tokp, y0, y1, nullptr, nullptr, 0);
  }
  combine_kernel<<<NTOK, 256, 0, stream>>>(y0, y1, te, tw, pidx, b2, outF);
}